// Round 2
// baseline (10598.029 us; speedup 1.0000x reference)
//
#include <hip/hip_runtime.h>

// ScaledODENetFE: forward-Euler scan, T=44100, B=32, F=1, S=16, H=64.
// One wave per batch; lane k owns hidden unit k. Chain-latency bound.
// R13 = R12 with the cross-row DS combine ELIMINATED (DS-free recurrence):
//  - The 3-DS combine (^16/^32/^48) + 2 adds only fed the R-dot and pb0.
//    By linearity R = C2 + sum_{l=0}^{63} Pb_l * w1yd[l&15]: the dual-basis
//    parities use only lane bits 0-3, so lane l's butterfly output Pb_l is
//    its row's partial for s = l&15 (this is what made the old 16-readlane
//    dot pair lane j with w1yd[j]). We readlane all 64 raw Pb values and
//    run 4 pk-fma chains (one per 16-lane row group) on the SAME wy2 pairs.
//    Trades ~140 cyc extra issue for the ~200-cyc DS round-trip dead window.
//  - pb0 = (Pb0+Pb16)+(Pb32+Pb48): bit-identical rounding tree to R12's
//    Pc_0, so the y0 path is unchanged. R reassociation is sanctioned
//    (R10 post-mortem: "Reassociation inside R is free").
// Kept from R12: constant-64 main loop + peeled last step + 3-step tail,
// unroll 9, pk-packed dot, r-form with -2-scaled W2, K-fold carry,
// zbase precompute off-chain.
// permlane16/32_swap BANNED (R4/R5). LDS P-broadcast BANNED (R7).
// R10's V-reconstruction BANNED (cancellation noise in carry).

#define SRATE 44100.0f
#define T_TOTAL 44100
#define BATCH 32
#define HID 64
#define ST 16
#define KSCALE 2.8853900817779268f   // 2*log2(e)

typedef float v2f __attribute__((ext_vector_type(2)));

template <int CTRL>
__device__ __forceinline__ float dppmov(float x) {
    return __builtin_bit_cast(float,
        __builtin_amdgcn_update_dpp(0, __builtin_bit_cast(int, x),
                                    CTRL, 0xF, 0xF, false));
}

__device__ __forceinline__ float bcast(float v, int lane) {
    return __builtin_bit_cast(float,
        __builtin_amdgcn_readlane(__builtin_bit_cast(int, v), lane));
}

__device__ __forceinline__ int parity(int v) { return __builtin_popcount(v) & 1; }

__global__ __launch_bounds__(64, 1)
void ScaledODENetFE_kernel(const float* __restrict__ x,
                           const float* __restrict__ W1,
                           const float* __restrict__ b1,
                           const float* __restrict__ W2,
                           const float* __restrict__ b2v,
                           float* __restrict__ out) {
    const int b = blockIdx.x;      // batch element
    const int lane = threadIdx.x;  // hidden unit k
    const int TM1 = T_TOTAL - 1;   // 44099 scan steps = 689*64 + 3
    const int NFULL = 689;

    // ---- one-time precompute (lane k) ----
    const float w1xK = W1[lane] * KSCALE;       // K-scaled x weight
    float w1yd[ST];                             // K * W1[1+s][lane] / sr
    #pragma unroll
    for (int s = 0; s < ST; ++s)
        w1yd[s] = (W1[(1 + s) * HID + lane] / SRATE) * KSCALE;

    // C2 = sum_s (b2[s] + pconst_s) * w1yd[s];  pconst_s = sum_k W2[k,s].
    float C2 = 0.f;
    #pragma unroll
    for (int s = 0; s < ST; ++s) C2 = fmaf(b2v[s], w1yd[s], C2);
    float pconst0 = 0.f;
    for (int s = 0; s < ST; ++s) {
        float pc = 0.f;
        for (int k = 0; k < HID; ++k) pc += W2[k * ST + s];
        C2 = fmaf(pc, w1yd[s], C2);
        if (s == 0) pconst0 = pc;
    }
    // pk-dot weight pairs (per-lane VGPR pairs), shared by all 4 row groups.
    v2f wy2[8];
    #pragma unroll
    for (int m = 0; m < 8; ++m) wy2[m] = (v2f){w1yd[2 * m], w1yd[2 * m + 1]};
    const v2f C2v = (v2f){C2, 0.f};             // loop-invariant seed

    // Dual-basis lane phis for the permuted W2 layout (XOR gens 1,2,7,8),
    // weights pre-scaled by -2 (r-form: p = pconst - 2 * W2^T r).
    const int p1 = parity(lane & 5), p2 = parity(lane & 6);
    const int p3 = (lane >> 2) & 1, p4 = (lane >> 3) & 1;
    float wA[8], wB[8];
    #pragma unroll
    for (int j = 0; j < 8; ++j) {
        const int i = 2 * j;
        const int c1 = (i & 1) ^ p1;
        const int c2 = ((i >> 1) & 1) ^ p2;
        const int c3 = ((i >> 2) & 1) ^ p3;
        const int c4 = ((i >> 3) & 1) ^ p4;
        const int s = (c1 ? 1 : 0) ^ (c2 ? 2 : 0) ^ (c3 ? 7 : 0) ^ (c4 ? 8 : 0);
        wA[j] = -2.f * W2[lane * ST + s];
        wB[j] = -2.f * W2[(lane ^ 1) * ST + s];
    }
    v2f wA2[4], wB2[4];
    #pragma unroll
    for (int m = 0; m < 4; ++m) {
        wA2[m] = (v2f){wA[2 * m], wA[2 * m + 1]};
        wB2[m] = (v2f){wB[2 * m], wB[2 * m + 1]};
    }

    const float b20 = b2v[0];

    float V  = b1[lane] * KSCALE;               // K-scaled carry (y starts 0)
    float y0 = 0.f;

    if (lane == 0) out[b] = 0.f;                // row t=0 is zeros

    // Lane l holds x[(t0+l)*B + b]; prefetch one chunk ahead.
    float xv = x[lane * BATCH + b];
    float z = fmaf(bcast(xv, 0), w1xK, V);      // z_0 (K-scaled)

    // One recurrence step. Consumes z; produces next z, updates V; returns
    // this step's combined Pb0 (for the y0 path) through pb0.
    auto STEP = [&](float xtn, float& pb0) {
        // tanh in r-form: t=exp2(z); r=rcp(t+1). (h = 1-2r implicit;
        // saturation via inf/0 semantics, no clamp — R8-validated.)
        float t = __builtin_amdgcn_exp2f(z);
        float r = __builtin_amdgcn_rcpf(t + 1.f);

        // Off-chain prep for next step's z (uses pre-update V; +R applied once).
        float zbase = fmaf(xtn, w1xK, V);

        // Stage 1 (xor1, fused, packed) on r with -2-scaled weights.
        float rx = dppmov<0xB1>(r);             // quad_perm [1,0,3,2]
        v2f r2v = (v2f){r, r};
        v2f rx2 = (v2f){rx, rx};
        v2f u1p[4];
        #pragma unroll
        for (int m = 0; m < 4; ++m)
            u1p[m] = __builtin_elementwise_fma(rx2, wB2[m], r2v * wA2[m]);

        // Stage 2 (xor2 = quad_perm [2,3,0,1]).
        float u2[4];
        #pragma unroll
        for (int m = 0; m < 4; ++m)
            u2[m] = u1p[m].x + dppmov<0x4E>(u1p[m].y);

        // Stage 3 (xor7 = row_half_mirror).
        float u3a = u2[0] + dppmov<0x141>(u2[1]);
        float u3b = u2[2] + dppmov<0x141>(u2[3]);

        // Stage 4 (xor8 = row_ror:8).
        float Pb = u3a + dppmov<0x128>(u3b);
        // Lane l now holds its ROW's partial sum for s = l&15.

        // DS-free cross-row: readlane all 64 row-partials; R-dot reassociated
        // as 4 independent pk-fma chains (one per row group), same wy2 pairs.
        float pl[64];
        #pragma unroll
        for (int l = 0; l < 64; ++l) pl[l] = bcast(Pb, l);

        v2f a0 = __builtin_elementwise_fma((v2f){pl[0], pl[1]}, wy2[0], C2v);
        v2f a1 = (v2f){pl[16], pl[17]} * wy2[0];
        v2f a2 = (v2f){pl[32], pl[33]} * wy2[0];
        v2f a3 = (v2f){pl[48], pl[49]} * wy2[0];
        #pragma unroll
        for (int m = 1; m < 8; ++m) {
            a0 = __builtin_elementwise_fma((v2f){pl[2 * m],      pl[2 * m + 1]},      wy2[m], a0);
            a1 = __builtin_elementwise_fma((v2f){pl[16 + 2 * m], pl[16 + 2 * m + 1]}, wy2[m], a1);
            a2 = __builtin_elementwise_fma((v2f){pl[32 + 2 * m], pl[32 + 2 * m + 1]}, wy2[m], a2);
            a3 = __builtin_elementwise_fma((v2f){pl[48 + 2 * m], pl[48 + 2 * m + 1]}, wy2[m], a3);
        }
        v2f accs = (a0 + a1) + (a2 + a3);
        float R = accs.x + accs.y;

        // y0 path: same rounding tree as R12's Pc_0.
        pb0 = (pl[0] + pl[16]) + (pl[32] + pl[48]);

        z = zbase + R;       // critical-path tail: single add
        V = V + R;           // off-chain, feeds next step's zbase
    };

    // ---- 689 full 64-step blocks ----
    for (int blk = 0; blk < NFULL; ++blk) {
        const int t0 = blk * 64;
        // Next chunk; first touched at the peeled step (63 steps later),
        // so its vmcnt wait is fully hidden.
        float xvn = x[min(t0 + 64 + lane, TM1 - 1) * BATCH + b];
        float outy = 0.f;
        float pb0;

        #pragma unroll 9
        for (int kk = 0; kk < 63; ++kk) {
            STEP(bcast(xv, kk + 1), pb0);
            // y0 path: p0 = pconst0 + Pc0 (full magnitude), b20 at store.
            y0 += pconst0 + pb0;
            outy = (kk == lane) ? y0 : outy;
        }
        // Peeled kk=63: next-x comes from lane 0 of the prefetched chunk.
        STEP(bcast(xvn, 0), pb0);
        y0 += pconst0 + pb0;
        outy = (63 == lane) ? y0 : outy;

        // Store: add back n*b2[0], one IEEE div, coalesced.
        const int n = t0 + 1 + lane;
        out[n * BATCH + b] = fmaf((float)n, b20, outy) / SRATE;
        xv = xvn;
    }

    // ---- tail: 3 steps (n = 44097..44099) ----
    {
        const int t0 = NFULL * 64;              // 44096
        float outy = 0.f;
        float pb0;
        #pragma unroll
        for (int kk = 0; kk < 3; ++kk) {
            STEP(bcast(xv, kk + 1), pb0);
            y0 += pconst0 + pb0;
            outy = (kk == lane) ? y0 : outy;
        }
        if (lane < 3) {
            const int n = t0 + 1 + lane;
            out[n * BATCH + b] = fmaf((float)n, b20, outy) / SRATE;
        }
    }
}

extern "C" void kernel_launch(void* const* d_in, const int* in_sizes, int n_in,
                              void* d_out, int out_size, void* d_ws, size_t ws_size,
                              hipStream_t stream) {
    const float* x  = (const float*)d_in[0];
    const float* W1 = (const float*)d_in[1];
    const float* b1 = (const float*)d_in[2];
    const float* W2 = (const float*)d_in[3];
    const float* b2 = (const float*)d_in[4];
    float* out = (float*)d_out;

    ScaledODENetFE_kernel<<<BATCH, 64, 0, stream>>>(x, W1, b1, W2, b2, out);
}

// Round 3
// 5755.123 us; speedup vs baseline: 1.8415x; 1.8415x over previous
//
#include <hip/hip_runtime.h>

// ScaledODENetFE: forward-Euler scan, T=44100, B=32, F=1, S=16, H=64.
// One wave per batch; lane k owns hidden unit k. Chain-latency bound.
// R14 = R12 (6571us kernel) with ONE delta: the cross-row DS combine
// (3x ds_swizzle/bpermute, ~120-200cy round trip ON the chain) is replaced
// by permlane16/32 swaps (VALU, ~8cy each) using the pair-sum idiom:
//   with a=b=Pb, after v_permlane16_swap_b32 a,b the two regs jointly hold
//   lanes {l, l^16}, so a+b = Pb_l + Pb_{l^16} under any swap orientation;
//   repeat with 32-swap -> Pc = (Pb+Pb16) + (Pb32+Pb48), the SAME rounding
//   tree as R12's DS combine (absmax must stay bit-identical).
// Re-litigating the R4/R5 permlane ban deliberately: catalog evidence
// (m255: permlane32_swap 1.20x ds_bpermute even in THROUGHPUT; T12 uses it
// in production) + this is a LATENCY chain (~15x latency gap). Suspected
// original ban cause: swap used as a pure function (it writes BOTH
// operands) -> wrong results. The "+v","+v" inline-asm form encodes the
// dual-write exactly; pair-sum makes orientation irrelevant.
// R13 readlane-all REVERTED (+60% regression): 48 extra readlanes + v2f
// packing movs serialized ON the chain. Post-DS broadcast stays at 16
// readlanes; never add issue on the chain to remove latency.
// Kept from R12: constant-64 main loop + peeled last step + 3-step tail,
// unroll 9, pk-packed 16-readlane dot, r-form with -2-scaled W2, K-fold
// carry, zbase precompute off-chain.
// LDS P-broadcast BANNED (R7). R10's V-reconstruction BANNED (carry noise).

#define SRATE 44100.0f
#define T_TOTAL 44100
#define BATCH 32
#define HID 64
#define ST 16
#define KSCALE 2.8853900817779268f   // 2*log2(e)

typedef float v2f __attribute__((ext_vector_type(2)));

template <int CTRL>
__device__ __forceinline__ float dppmov(float x) {
    return __builtin_bit_cast(float,
        __builtin_amdgcn_update_dpp(0, __builtin_bit_cast(int, x),
                                    CTRL, 0xF, 0xF, false));
}

__device__ __forceinline__ float bcast(float v, int lane) {
    return __builtin_bit_cast(float,
        __builtin_amdgcn_readlane(__builtin_bit_cast(int, v), lane));
}

__device__ __forceinline__ int parity(int v) { return __builtin_popcount(v) & 1; }

__global__ __launch_bounds__(64, 1)
void ScaledODENetFE_kernel(const float* __restrict__ x,
                           const float* __restrict__ W1,
                           const float* __restrict__ b1,
                           const float* __restrict__ W2,
                           const float* __restrict__ b2v,
                           float* __restrict__ out) {
    const int b = blockIdx.x;      // batch element
    const int lane = threadIdx.x;  // hidden unit k
    const int TM1 = T_TOTAL - 1;   // 44099 scan steps = 689*64 + 3
    const int NFULL = 689;

    // ---- one-time precompute (lane k) ----
    const float w1xK = W1[lane] * KSCALE;       // K-scaled x weight
    float w1yd[ST];                             // K * W1[1+s][lane] / sr
    #pragma unroll
    for (int s = 0; s < ST; ++s)
        w1yd[s] = (W1[(1 + s) * HID + lane] / SRATE) * KSCALE;

    // C2 = sum_s (b2[s] + pconst_s) * w1yd[s];  pconst_s = sum_k W2[k,s].
    float C2 = 0.f;
    #pragma unroll
    for (int s = 0; s < ST; ++s) C2 = fmaf(b2v[s], w1yd[s], C2);
    float pconst0 = 0.f;
    for (int s = 0; s < ST; ++s) {
        float pc = 0.f;
        for (int k = 0; k < HID; ++k) pc += W2[k * ST + s];
        C2 = fmaf(pc, w1yd[s], C2);
        if (s == 0) pconst0 = pc;
    }
    // pk-dot weight pairs (per-lane VGPR pairs).
    v2f wy2[8];
    #pragma unroll
    for (int m = 0; m < 8; ++m) wy2[m] = (v2f){w1yd[2 * m], w1yd[2 * m + 1]};
    const v2f C2v = (v2f){C2, 0.f};             // loop-invariant seed

    // Dual-basis lane phis for the permuted W2 layout (XOR gens 1,2,7,8),
    // weights pre-scaled by -2 (r-form: p = pconst - 2 * W2^T r).
    const int p1 = parity(lane & 5), p2 = parity(lane & 6);
    const int p3 = (lane >> 2) & 1, p4 = (lane >> 3) & 1;
    float wA[8], wB[8];
    #pragma unroll
    for (int j = 0; j < 8; ++j) {
        const int i = 2 * j;
        const int c1 = (i & 1) ^ p1;
        const int c2 = ((i >> 1) & 1) ^ p2;
        const int c3 = ((i >> 2) & 1) ^ p3;
        const int c4 = ((i >> 3) & 1) ^ p4;
        const int s = (c1 ? 1 : 0) ^ (c2 ? 2 : 0) ^ (c3 ? 7 : 0) ^ (c4 ? 8 : 0);
        wA[j] = -2.f * W2[lane * ST + s];
        wB[j] = -2.f * W2[(lane ^ 1) * ST + s];
    }
    v2f wA2[4], wB2[4];
    #pragma unroll
    for (int m = 0; m < 4; ++m) {
        wA2[m] = (v2f){wA[2 * m], wA[2 * m + 1]};
        wB2[m] = (v2f){wB[2 * m], wB[2 * m + 1]};
    }

    const float b20 = b2v[0];

    float V  = b1[lane] * KSCALE;               // K-scaled carry (y starts 0)
    float y0 = 0.f;

    if (lane == 0) out[b] = 0.f;                // row t=0 is zeros

    // Lane l holds x[(t0+l)*B + b]; prefetch one chunk ahead.
    float xv = x[lane * BATCH + b];
    float z = fmaf(bcast(xv, 0), w1xK, V);      // z_0 (K-scaled)

    // One recurrence step. Consumes z; produces next z, updates V; returns
    // this step's combined Pb0 (for the y0 path) through pb0.
    auto STEP = [&](float xtn, float& pb0) {
        // tanh in r-form: t=exp2(z); r=rcp(t+1). (h = 1-2r implicit;
        // saturation via inf/0 semantics, no clamp — R8-validated.)
        float t = __builtin_amdgcn_exp2f(z);
        float r = __builtin_amdgcn_rcpf(t + 1.f);

        // Off-chain prep for next step's z (uses pre-update V; +R applied once).
        float zbase = fmaf(xtn, w1xK, V);

        // Stage 1 (xor1, fused, packed) on r with -2-scaled weights.
        float rx = dppmov<0xB1>(r);             // quad_perm [1,0,3,2]
        v2f r2v = (v2f){r, r};
        v2f rx2 = (v2f){rx, rx};
        v2f u1p[4];
        #pragma unroll
        for (int m = 0; m < 4; ++m)
            u1p[m] = __builtin_elementwise_fma(rx2, wB2[m], r2v * wA2[m]);

        // Stage 2 (xor2 = quad_perm [2,3,0,1]).
        float u2[4];
        #pragma unroll
        for (int m = 0; m < 4; ++m)
            u2[m] = u1p[m].x + dppmov<0x4E>(u1p[m].y);

        // Stage 3 (xor7 = row_half_mirror).
        float u3a = u2[0] + dppmov<0x141>(u2[1]);
        float u3b = u2[2] + dppmov<0x141>(u2[3]);

        // Stage 4 (xor8 = row_ror:8).
        float Pb = u3a + dppmov<0x128>(u3b);
        // Lane l now holds its ROW's partial sum for s = l&15.

        // Cross-row combine via permlane swaps (VALU latency, no DS).
        // Pair-sum idiom: a=b=Pb; after the swap the two regs jointly hold
        // lanes {l, l^16}, so a+b = Pb_l + Pb_{l^16} regardless of swap
        // orientation. Then 32-swap on the sum. Rounding tree identical to
        // R12's (Pb + a16) + (a32 + a48).
        float sa = Pb, sb = Pb;
        asm("v_permlane16_swap_b32 %0, %1" : "+v"(sa), "+v"(sb));
        float y16 = sa + sb;                    // Pb_l + Pb_{l^16}
        float sc = y16, sd = y16;
        asm("v_permlane32_swap_b32 %0, %1" : "+v"(sc), "+v"(sd));
        float Pc = sc + sd;                     // full 4-row sum
        // Lane holds Pc_{lane&15}; p_s = pconst_s + Pc_s.

        // R = C2 + sum_s Pc_s*w1yd[s]: pk-packed, 2 chains of 4 pk_fma.
        // Broadcast pairs are wave-uniform -> SGPR-pair scalar operands.
        v2f p01 = (v2f){bcast(Pc, 0),  bcast(Pc, 1)};
        v2f p23 = (v2f){bcast(Pc, 2),  bcast(Pc, 3)};
        v2f p45 = (v2f){bcast(Pc, 4),  bcast(Pc, 5)};
        v2f p67 = (v2f){bcast(Pc, 6),  bcast(Pc, 7)};
        v2f p89 = (v2f){bcast(Pc, 8),  bcast(Pc, 9)};
        v2f pAB = (v2f){bcast(Pc, 10), bcast(Pc, 11)};
        v2f pCD = (v2f){bcast(Pc, 12), bcast(Pc, 13)};
        v2f pEF = (v2f){bcast(Pc, 14), bcast(Pc, 15)};
        v2f acc_a = __builtin_elementwise_fma(p01, wy2[0], C2v);
        acc_a = __builtin_elementwise_fma(p23, wy2[1], acc_a);
        acc_a = __builtin_elementwise_fma(p45, wy2[2], acc_a);
        acc_a = __builtin_elementwise_fma(p67, wy2[3], acc_a);
        v2f acc_b = p89 * wy2[4];
        acc_b = __builtin_elementwise_fma(pAB, wy2[5], acc_b);
        acc_b = __builtin_elementwise_fma(pCD, wy2[6], acc_b);
        acc_b = __builtin_elementwise_fma(pEF, wy2[7], acc_b);
        v2f accs = acc_a + acc_b;
        float R = accs.x + accs.y;

        pb0 = p01.x;         // combined Pb0 for the y0 path (CSE'd readlane)
        z = zbase + R;       // critical-path tail: single add
        V = V + R;           // off-chain, feeds next step's zbase
    };

    // ---- 689 full 64-step blocks ----
    for (int blk = 0; blk < NFULL; ++blk) {
        const int t0 = blk * 64;
        // Next chunk; first touched at the peeled step (63 steps later),
        // so its vmcnt wait is fully hidden.
        float xvn = x[min(t0 + 64 + lane, TM1 - 1) * BATCH + b];
        float outy = 0.f;
        float pb0;

        #pragma unroll 9
        for (int kk = 0; kk < 63; ++kk) {
            STEP(bcast(xv, kk + 1), pb0);
            // y0 path: p0 = pconst0 + Pc0 (full magnitude), b20 at store.
            y0 += pconst0 + pb0;
            outy = (kk == lane) ? y0 : outy;
        }
        // Peeled kk=63: next-x comes from lane 0 of the prefetched chunk.
        STEP(bcast(xvn, 0), pb0);
        y0 += pconst0 + pb0;
        outy = (63 == lane) ? y0 : outy;

        // Store: add back n*b2[0], one IEEE div, coalesced.
        const int n = t0 + 1 + lane;
        out[n * BATCH + b] = fmaf((float)n, b20, outy) / SRATE;
        xv = xvn;
    }

    // ---- tail: 3 steps (n = 44097..44099) ----
    {
        const int t0 = NFULL * 64;              // 44096
        float outy = 0.f;
        float pb0;
        #pragma unroll
        for (int kk = 0; kk < 3; ++kk) {
            STEP(bcast(xv, kk + 1), pb0);
            y0 += pconst0 + pb0;
            outy = (kk == lane) ? y0 : outy;
        }
        if (lane < 3) {
            const int n = t0 + 1 + lane;
            out[n * BATCH + b] = fmaf((float)n, b20, outy) / SRATE;
        }
    }
}

extern "C" void kernel_launch(void* const* d_in, const int* in_sizes, int n_in,
                              void* d_out, int out_size, void* d_ws, size_t ws_size,
                              hipStream_t stream) {
    const float* x  = (const float*)d_in[0];
    const float* W1 = (const float*)d_in[1];
    const float* b1 = (const float*)d_in[2];
    const float* W2 = (const float*)d_in[3];
    const float* b2 = (const float*)d_in[4];
    float* out = (float*)d_out;

    ScaledODENetFE_kernel<<<BATCH, 64, 0, stream>>>(x, W1, b1, W2, b2, out);
}